// Round 6
// baseline (323.554 us; speedup 1.0000x reference)
//
#include <hip/hip_runtime.h>
#include <math.h>

#define N_TOK 16384
#define D_MODEL 2048
#define N_EXP 64
#define CAPACITY 640
#define NREP 8
#define NS 64  // K steps of 32

typedef __attribute__((ext_vector_type(8))) _Float16 h8;
typedef __attribute__((ext_vector_type(4))) float f4;

// ---------------- K0: W -> frag-tiled fp16 hi/lo chunks (W' = W*2^10) -------
// chunk c = s*4 + eg  (s = k/32, eg = e/16). Chunk = 64 lanes x 8 halves (1KB).
// lane l of chunk c holds e = (c&3)*16 + (l&15), k = (c>>2)*32 + (l>>4)*8.
__global__ __launch_bounds__(256) void k0_cvtw(const float* __restrict__ W,
                                               _Float16* __restrict__ WTH,
                                               _Float16* __restrict__ WTL) {
  const int t = threadIdx.x;
  const int lane = t & 63;
  const int c = blockIdx.x * 4 + (t >> 6);
  const int e = (c & 3) * 16 + (lane & 15);
  const int k = (c >> 2) * 32 + (lane >> 4) * 8;
  const float* src = W + (size_t)e * D_MODEL + k;
  const float4 a = *(const float4*)src;
  const float4 b = *(const float4*)(src + 4);
  const float f[8] = {a.x, a.y, a.z, a.w, b.x, b.y, b.z, b.w};
  h8 hh, ll;
#pragma unroll
  for (int j = 0; j < 8; j++) {
    const float s = f[j] * 1024.f;
    const _Float16 h = (_Float16)s;
    hh[j] = h;
    ll[j] = (_Float16)((s - (float)h) * 1024.f);
  }
  *(h8*)(WTH + c * 512 + lane * 8) = hh;
  *(h8*)(WTL + c * 512 + lane * 8) = ll;
}

// ---------------- K12: barrier-free MFMA GEMM + softmax/top2/hist/z ---------
// 1024 blocks x 256 thr (4 waves). Wave wn owns 16 tokens x 16 experts.
// x,W stream global->reg in frag layout. 8-slot x prefetch (7-step lead),
// 2-slot W prefetch. sched_barrier(0) per STEP pins load issue order so the
// compiler cannot sink prefetches to their use (round-5 failure: VGPR=56).
__global__ __launch_bounds__(256, 4) void k12_gemm_softmax(
    const float* __restrict__ x, const _Float16* __restrict__ WTH,
    const _Float16* __restrict__ WTL, float* __restrict__ rw_out,
    int2* __restrict__ top12, float2* __restrict__ wts,
    int* __restrict__ histR, float* __restrict__ zR) {
  __shared__ float slog[16][65];
  __shared__ float zred[4];

  const int t = threadIdx.x;
  const int lane = t & 63;
  const int wn = t >> 6;  // expert quarter (0..3)
  const int m0 = blockIdx.x * 16;
  const int rep = blockIdx.x & (NREP - 1);

  const int frow = lane & 15;
  const int fk = (lane >> 4) * 8;

  const float* xg = x + (size_t)(m0 + frow) * D_MODEL + fk;
  const _Float16* wth = WTH + wn * 512 + lane * 8;  // + s*2048
  const _Float16* wtl = WTL + wn * 512 + lane * 8;

  float4 xr[8][2];
  h8 wh_[2], wl_[2];
  f4 acc1 = (f4)(0.f), acc2 = (f4)(0.f);

#define LX(sl, s)                         \
  {                                       \
    const float* p_ = xg + (s) * 32;      \
    xr[sl][0] = *(const float4*)p_;       \
    xr[sl][1] = *(const float4*)(p_ + 4); \
  }
#define LW(sl, s)                               \
  {                                             \
    wh_[sl] = *(const h8*)(wth + (s) * 2048);   \
    wl_[sl] = *(const h8*)(wtl + (s) * 2048);   \
  }
#define CVT_MFMA(xs, ws)                                                  \
  {                                                                       \
    h8 ah, al;                                                            \
    const float xf[8] = {xr[xs][0].x, xr[xs][0].y, xr[xs][0].z,           \
                         xr[xs][0].w, xr[xs][1].x, xr[xs][1].y,           \
                         xr[xs][1].z, xr[xs][1].w};                       \
    _Pragma("unroll") for (int j = 0; j < 8; j++) {                       \
      const _Float16 a_ = (_Float16)xf[j];                                \
      ah[j] = a_;                                                         \
      al[j] = (_Float16)((xf[j] - (float)a_) * 1024.f);                   \
    }                                                                     \
    acc1 = __builtin_amdgcn_mfma_f32_16x16x32_f16(ah, wh_[ws], acc1, 0, 0, \
                                                  0);                      \
    acc2 = __builtin_amdgcn_mfma_f32_16x16x32_f16(al, wh_[ws], acc2, 0, 0, \
                                                  0);                      \
    acc2 = __builtin_amdgcn_mfma_f32_16x16x32_f16(ah, wl_[ws], acc2, 0, 0, \
                                                  0);                      \
  }
  // full step: compute s, refill W slot with s+2, x slot with s+8, pin.
#define STEP_FULL(xs, ws, s)             \
  {                                      \
    CVT_MFMA(xs, ws);                    \
    LW(ws, (s) + 2);                     \
    LX(xs, (s) + 8);                     \
    __builtin_amdgcn_sched_barrier(0);   \
  }
#define STEP_W(xs, ws, s)                \
  {                                      \
    CVT_MFMA(xs, ws);                    \
    LW(ws, (s) + 2);                     \
    __builtin_amdgcn_sched_barrier(0);   \
  }
#define STEP_N(xs, ws)                   \
  {                                      \
    CVT_MFMA(xs, ws);                    \
    __builtin_amdgcn_sched_barrier(0);   \
  }

  // prologue: x steps 0-7 -> slots 0-7; W steps 0-1 -> slots 0-1
  LX(0, 0); LX(1, 1); LX(2, 2); LX(3, 3);
  LX(4, 4); LX(5, 5); LX(6, 6); LX(7, 7);
  LW(0, 0); LW(1, 1);
  __builtin_amdgcn_sched_barrier(0);

  for (int g = 0; g < 56; g += 8) {  // steps 0..55: unconditional refills
    STEP_FULL(0, 0, g);
    STEP_FULL(1, 1, g + 1);
    STEP_FULL(2, 0, g + 2);
    STEP_FULL(3, 1, g + 3);
    STEP_FULL(4, 0, g + 4);
    STEP_FULL(5, 1, g + 5);
    STEP_FULL(6, 0, g + 6);
    STEP_FULL(7, 1, g + 7);
  }
  // steps 56..61: W refill only; 62..63: no refill
  STEP_W(0, 0, 56);
  STEP_W(1, 1, 57);
  STEP_W(2, 0, 58);
  STEP_W(3, 1, 59);
  STEP_W(4, 0, 60);
  STEP_W(5, 1, 61);
  STEP_N(6, 0);
  STEP_N(7, 1);

  // epilogue: C layout col=lane&15 (expert within wave), row=(lane>>4)*4+r
  const int cg = lane >> 4, ci = lane & 15;
#pragma unroll
  for (int r = 0; r < 4; r++) {
    const float v = (acc1[r] + acc2[r] * 0.0009765625f) * 0.0009765625f;
    slog[cg * 4 + r][wn * 16 + ci] = v;
  }
  __syncthreads();

  // ---- softmax / top2 / hist / z tail (4 tokens per wave) ----
  float z_acc = 0.f;
  for (int tt = 0; tt < 4; tt++) {
    const int tloc = wn * 4 + tt;
    const int n = m0 + tloc;
    const float v = slog[tloc][lane];
    z_acc += v * v;
    float mx = v;
#pragma unroll
    for (int off = 32; off; off >>= 1) mx = fmaxf(mx, __shfl_xor(mx, off));
    const float p = __expf(v - mx);
    float ssum = p;
#pragma unroll
    for (int off = 32; off; off >>= 1) ssum += __shfl_xor(ssum, off);
    const float rw = p / ssum;
    rw_out[(size_t)n * N_EXP + lane] = rw;

    const unsigned long long b1 = __ballot(v == mx);
    const int i1 = __builtin_ctzll(b1);
    float v2 = (lane == i1) ? -INFINITY : v;
#pragma unroll
    for (int off = 32; off; off >>= 1) v2 = fmaxf(v2, __shfl_xor(v2, off));
    const unsigned long long b2 = __ballot(v == v2) & ~(1ull << i1);
    const int i2 = __builtin_ctzll(b2);
    const float rw1 = __shfl(rw, i1);
    const float rw2 = __shfl(rw, i2);
    if (lane == 0) {
      const float denom = rw1 + rw2 + 1e-8f;
      top12[n] = make_int2(i1, i2);
      wts[n] = make_float2(rw1 / denom, rw2 / denom);
      atomicAdd(&histR[(rep * N_EXP + i1) * 16], 1);
    }
  }
#pragma unroll
  for (int off = 32; off; off >>= 1) z_acc += __shfl_xor(z_acc, off);
  if (lane == 0) zred[wn] = z_acc;
  __syncthreads();
  if (t == 0) atomicAdd(&zR[rep * 16], zred[0] + zred[1] + zred[2] + zred[3]);
}

// ---------------- K3: wave-per-token dispatch mask + counts -----------------
__global__ __launch_bounds__(256) void k3_dispatch(
    const int2* __restrict__ top12, const float2* __restrict__ wts,
    const int* __restrict__ histR, float* __restrict__ mask_out,
    float* __restrict__ cntR) {
  const int lane = threadIdx.x & 63;
  const int wid = threadIdx.x >> 6;
  const int n = blockIdx.x * 4 + wid;
  const int rep = blockIdx.x & (NREP - 1);

  const int2 ij = top12[n];
  const float2 w = wts[n];
  int h = 0;
#pragma unroll
  for (int r = 0; r < NREP; r++) h += histR[(r * N_EXP + ij.y) * 16];
  const bool allowed = h < CAPACITY;
  const float ssum = w.x + (allowed ? w.y : 0.f);
  const float inv = 1.f / (ssum + 1e-8f);
  float val = 0.f;
  if (lane == ij.x) val = w.x * inv;
  else if (allowed && lane == ij.y) val = w.y * inv;
  mask_out[(size_t)n * N_EXP + lane] = val;
  if (val != 0.f) atomicAdd(&cntR[(rep * N_EXP + lane) * 16], val);
}

// ---------------- K4: scalar loss -------------------------------------------
__global__ void k4_loss(const float* __restrict__ cntR,
                        const float* __restrict__ zR,
                        float* __restrict__ loss_out) {
  const int lane = threadIdx.x;
  float c = 0.f;
#pragma unroll
  for (int r = 0; r < NREP; r++) c += cntR[(r * N_EXP + lane) * 16];
  const float d = (c - 512.0f) * (1.0f / 16384.0f);
  float v = d * d;
#pragma unroll
  for (int off = 32; off; off >>= 1) v += __shfl_xor(v, off);
  if (lane == 0) {
    float z = 0.f;
#pragma unroll
    for (int r = 0; r < NREP; r++) z += zR[r * 16];
    const float lb = v * (1.0f / 64.0f);
    loss_out[0] = 0.001f * (z * (1.0f / (16384.0f * 64.0f))) + 0.001f * lb;
  }
}

extern "C" void kernel_launch(void* const* d_in, const int* in_sizes, int n_in,
                              void* d_out, int out_size, void* d_ws,
                              size_t ws_size, hipStream_t stream) {
  const float* x = (const float*)d_in[0];
  const float* W = (const float*)d_in[1];
  float* out = (float*)d_out;
  float* rw_out = out;
  float* mask_out = out + (size_t)N_TOK * N_EXP;
  float* loss_out = out + 2 * (size_t)N_TOK * N_EXP;

  char* ws = (char*)d_ws;
  int* histR = (int*)ws;                     // 32 KB
  float* cntR = (float*)(ws + 32768);        // 32 KB
  float* zR = (float*)(ws + 65536);          // 512 B
  int2* top12 = (int2*)(ws + 131072);        // 128 KB
  float2* wts = (float2*)(ws + 262144);      // 128 KB
  _Float16* WTH = (_Float16*)(ws + 393216);  // 256 KB (frag-tiled hi)
  _Float16* WTL = (_Float16*)(ws + 655360);  // 256 KB (frag-tiled lo)

  hipMemsetAsync(histR, 0, 65536 + 512, stream);
  k0_cvtw<<<64, 256, 0, stream>>>(W, WTH, WTL);
  k12_gemm_softmax<<<1024, 256, 0, stream>>>(x, WTH, WTL, rw_out, top12, wts,
                                             histR, zR);
  k3_dispatch<<<N_TOK / 4, 256, 0, stream>>>(top12, wts, histR, mask_out,
                                             cntR);
  k4_loss<<<1, 64, 0, stream>>>(cntR, zR, loss_out);
}

// Round 8
// 228.860 us; speedup vs baseline: 1.4138x; 1.4138x over previous
//
#include <hip/hip_runtime.h>
#include <math.h>

#define N_TOK 16384
#define D_MODEL 2048
#define N_EXP 64
#define CAPACITY 640
#define NREP 8
#define TM 32      // tokens per block
#define NSTEP 32   // K steps of 64

typedef __attribute__((ext_vector_type(8))) _Float16 h8;
typedef __attribute__((ext_vector_type(4))) float f4;

#define AS1 __attribute__((address_space(1)))
#define AS3 __attribute__((address_space(3)))
__device__ __forceinline__ void gld16(const void* g, void* l) {
  __builtin_amdgcn_global_load_lds((const AS1 void*)g, (AS3 void*)l, 16, 0, 0);
}

// ---------------- K0: W -> gload-ready fp16 hi/lo chunks (W' = W*2^10) ------
// chunk c = s*16 + q, q = part*8 + ks*4 + nt. Chunk = 64 lanes x 8 halves (1KB).
// lane l: e = nt*16 + (l&15), k = s*64 + ks*32 + (l>>4)*8; part: 0=hi 1=lo.
__global__ __launch_bounds__(256) void k0_cvtw(const float* __restrict__ W,
                                               _Float16* __restrict__ WT) {
  const int lane = threadIdx.x & 63;
  const int c = blockIdx.x * 4 + (threadIdx.x >> 6);  // 0..511
  const int s = c >> 4, q = c & 15;
  const int part = q >> 3, ks = (q >> 2) & 1, nt = q & 3;
  const int e = nt * 16 + (lane & 15);
  const int k = s * 64 + ks * 32 + (lane >> 4) * 8;
  const float* src = W + (size_t)e * D_MODEL + k;
  const float4 a = *(const float4*)src;
  const float4 b = *(const float4*)(src + 4);
  const float f[8] = {a.x, a.y, a.z, a.w, b.x, b.y, b.z, b.w};
  h8 out;
#pragma unroll
  for (int j = 0; j < 8; j++) {
    const float sc = f[j] * 1024.f;
    const _Float16 h = (_Float16)sc;
    out[j] = part ? (_Float16)((sc - (float)h) * 1024.f) : h;
  }
  *(h8*)(WT + (size_t)c * 512 + lane * 8) = out;
}

// ---------------- K12: global_load_lds double-buffered MFMA GEMM + softmax --
// 512 blocks x 256 thr (4 waves) = 2 blocks/CU. Block = 32 tok x 64 exp.
// Wave w owns experts w*16..w*16+15, all 32 tokens (2 m-frags).
// x staged fp32 with XOR-pre-swizzled per-lane global source (linear LDS dest,
// swizzled ds_read -> conflict-free); W staged pre-split fp16 frag-linear.
// One barrier/K-step; stage(s+1) issued after barrier so drain overlaps compute.
__global__ __launch_bounds__(256, 2) void k12_gemm_softmax(
    const float* __restrict__ x, const _Float16* __restrict__ WT,
    float* __restrict__ rw_out, int2* __restrict__ top12,
    float2* __restrict__ wts, int* __restrict__ histR,
    float* __restrict__ zR) {
  __shared__ __align__(16) float XS[2][2048];      // [buf][32 rows][64 cols]
  __shared__ __align__(16) _Float16 WS[2][8192];   // [buf][16 chunks][512]
  __shared__ float slog[TM][65];
  __shared__ float zred[4];

  const int t = threadIdx.x;
  const int lane = t & 63;
  const int wid = t >> 6;
  const int m0 = blockIdx.x * TM;
  const int rep = blockIdx.x & (NREP - 1);

  // x staging: inst i = 2*wid + j covers rows i*4..i*4+3; lane l -> row
  // i*4+(l>>4), 16B-slot (l&15), global slot pre-swizzled by row&7.
  const int i0 = wid * 2;
  const int r0 = i0 * 4 + (lane >> 4);
  const int r1 = r0 + 4;
  const int s16 = lane & 15;
  const float* xs0 = x + (size_t)(m0 + r0) * D_MODEL + ((s16 ^ (r0 & 7)) * 4);
  const float* xs1 = x + (size_t)(m0 + r1) * D_MODEL + ((s16 ^ (r1 & 7)) * 4);
  // W staging: wave w issues chunks q = 4w..4w+3 of step s.
  const _Float16* wsrc = WT + (size_t)(wid * 4) * 512 + lane * 8;

  f4 acc1[2], acc2[2];
#pragma unroll
  for (int i = 0; i < 2; i++) {
    acc1[i] = (f4)(0.f);
    acc2[i] = (f4)(0.f);
  }

#define STAGE(buf, s)                                           \
  {                                                             \
    gld16(xs0 + (s) * 64, &XS[buf][i0 * 256]);                  \
    gld16(xs1 + (s) * 64, &XS[buf][i0 * 256 + 256]);            \
    _Pragma("unroll") for (int j2 = 0; j2 < 4; j2++)            \
        gld16(wsrc + (size_t)(s) * 8192 + j2 * 512,             \
              &WS[buf][(wid * 4 + j2) * 512]);                  \
  }

#define COMPUTE(buf)                                                           \
  {                                                                            \
    _Pragma("unroll") for (int ks = 0; ks < 2; ks++) {                         \
      const h8 bh = *(const h8*)&WS[buf][(ks * 4 + wid) * 512 + lane * 8];     \
      const h8 bl = *(const h8*)&WS[buf][(8 + ks * 4 + wid) * 512 + lane * 8]; \
      _Pragma("unroll") for (int mf = 0; mf < 2; mf++) {                       \
        const int row = mf * 16 + (lane & 15);                                 \
        const int cb = ks * 8 + (lane >> 4) * 2;                               \
        const int sw = lane & 7;                                               \
        const f4 a0 = *(const f4*)&XS[buf][row * 64 + ((cb ^ sw) * 4)];        \
        const f4 a1 = *(const f4*)&XS[buf][row * 64 + (((cb + 1) ^ sw) * 4)];  \
        h8 ah, al;                                                             \
        const float xf[8] = {a0[0], a0[1], a0[2], a0[3],                       \
                             a1[0], a1[1], a1[2], a1[3]};                      \
        _Pragma("unroll") for (int j = 0; j < 8; j++) {                        \
          const _Float16 hv = (_Float16)xf[j];                                 \
          ah[j] = hv;                                                          \
          al[j] = (_Float16)((xf[j] - (float)hv) * 1024.f);                    \
        }                                                                      \
        acc1[mf] = __builtin_amdgcn_mfma_f32_16x16x32_f16(ah, bh, acc1[mf],    \
                                                          0, 0, 0);            \
        acc2[mf] = __builtin_amdgcn_mfma_f32_16x16x32_f16(al, bh, acc2[mf],    \
                                                          0, 0, 0);            \
        acc2[mf] = __builtin_amdgcn_mfma_f32_16x16x32_f16(ah, bl, acc2[mf],    \
                                                          0, 0, 0);            \
      }                                                                        \
    }                                                                          \
  }

  STAGE(0, 0);
  int cur = 0;
  for (int s = 0; s < NSTEP; s++) {
    __syncthreads();  // drains DMAs -> buf[cur] ready; prev compute done
    if (s + 1 < NSTEP) STAGE(cur ^ 1, s + 1);
    COMPUTE(cur);
    cur ^= 1;
  }

  // epilogue: C layout col=lane&15 (expert within wave), row=(lane>>4)*4+r
  const int cg = lane >> 4, ci = lane & 15;
#pragma unroll
  for (int mf = 0; mf < 2; mf++)
#pragma unroll
    for (int r = 0; r < 4; r++) {
      const float v =
          (acc1[mf][r] + acc2[mf][r] * 0.0009765625f) * 0.0009765625f;
      slog[mf * 16 + cg * 4 + r][wid * 16 + ci] = v;
    }
  __syncthreads();

  // ---- softmax / top2 / hist / z tail (8 tokens per wave) ----
  float z_acc = 0.f;
  for (int tt = 0; tt < 8; tt++) {
    const int tloc = wid * 8 + tt;
    const int n = m0 + tloc;
    const float v = slog[tloc][lane];
    z_acc += v * v;
    float mx = v;
#pragma unroll
    for (int off = 32; off; off >>= 1) mx = fmaxf(mx, __shfl_xor(mx, off));
    const float p = __expf(v - mx);
    float ssum = p;
#pragma unroll
    for (int off = 32; off; off >>= 1) ssum += __shfl_xor(ssum, off);
    const float rw = p / ssum;
    rw_out[(size_t)n * N_EXP + lane] = rw;

    const unsigned long long b1 = __ballot(v == mx);
    const int i1 = __builtin_ctzll(b1);
    float v2 = (lane == i1) ? -INFINITY : v;
#pragma unroll
    for (int off = 32; off; off >>= 1) v2 = fmaxf(v2, __shfl_xor(v2, off));
    const unsigned long long b2 = __ballot(v == v2) & ~(1ull << i1);
    const int i2 = __builtin_ctzll(b2);
    const float rw1 = __shfl(rw, i1);
    const float rw2 = __shfl(rw, i2);
    if (lane == 0) {
      const float denom = rw1 + rw2 + 1e-8f;
      top12[n] = make_int2(i1, i2);
      wts[n] = make_float2(rw1 / denom, rw2 / denom);
      atomicAdd(&histR[(rep * N_EXP + i1) * 16], 1);
    }
  }
#pragma unroll
  for (int off = 32; off; off >>= 1) z_acc += __shfl_xor(z_acc, off);
  if (lane == 0) zred[wid] = z_acc;
  __syncthreads();
  if (t == 0) atomicAdd(&zR[rep * 16], zred[0] + zred[1] + zred[2] + zred[3]);
}

// ---------------- K3: wave-per-token dispatch mask + counts -----------------
__global__ __launch_bounds__(256) void k3_dispatch(
    const int2* __restrict__ top12, const float2* __restrict__ wts,
    const int* __restrict__ histR, float* __restrict__ mask_out,
    float* __restrict__ cntR) {
  const int lane = threadIdx.x & 63;
  const int wid = threadIdx.x >> 6;
  const int n = blockIdx.x * 4 + wid;
  const int rep = blockIdx.x & (NREP - 1);

  const int2 ij = top12[n];
  const float2 w = wts[n];
  int h = 0;
#pragma unroll
  for (int r = 0; r < NREP; r++) h += histR[(r * N_EXP + ij.y) * 16];
  const bool allowed = h < CAPACITY;
  const float ssum = w.x + (allowed ? w.y : 0.f);
  const float inv = 1.f / (ssum + 1e-8f);
  float val = 0.f;
  if (lane == ij.x) val = w.x * inv;
  else if (allowed && lane == ij.y) val = w.y * inv;
  mask_out[(size_t)n * N_EXP + lane] = val;
  if (val != 0.f) atomicAdd(&cntR[(rep * N_EXP + lane) * 16], val);
}

// ---------------- K4: scalar loss -------------------------------------------
__global__ void k4_loss(const float* __restrict__ cntR,
                        const float* __restrict__ zR,
                        float* __restrict__ loss_out) {
  const int lane = threadIdx.x;
  float c = 0.f;
#pragma unroll
  for (int r = 0; r < NREP; r++) c += cntR[(r * N_EXP + lane) * 16];
  const float d = (c - 512.0f) * (1.0f / 16384.0f);
  float v = d * d;
#pragma unroll
  for (int off = 32; off; off >>= 1) v += __shfl_xor(v, off);
  if (lane == 0) {
    float z = 0.f;
#pragma unroll
    for (int r = 0; r < NREP; r++) z += zR[r * 16];
    const float lb = v * (1.0f / 64.0f);
    loss_out[0] = 0.001f * (z * (1.0f / (16384.0f * 64.0f))) + 0.001f * lb;
  }
}

extern "C" void kernel_launch(void* const* d_in, const int* in_sizes, int n_in,
                              void* d_out, int out_size, void* d_ws,
                              size_t ws_size, hipStream_t stream) {
  const float* x = (const float*)d_in[0];
  const float* W = (const float*)d_in[1];
  float* out = (float*)d_out;
  float* rw_out = out;
  float* mask_out = out + (size_t)N_TOK * N_EXP;
  float* loss_out = out + 2 * (size_t)N_TOK * N_EXP;

  char* ws = (char*)d_ws;
  int* histR = (int*)ws;                    // 32 KB
  float* cntR = (float*)(ws + 32768);       // 32 KB
  float* zR = (float*)(ws + 65536);         // 512 B
  int2* top12 = (int2*)(ws + 131072);       // 128 KB
  float2* wts = (float2*)(ws + 262144);     // 128 KB
  _Float16* WT = (_Float16*)(ws + 393216);  // 512 KB (gload-ready chunks)

  hipMemsetAsync(histR, 0, 65536 + 512, stream);
  k0_cvtw<<<128, 256, 0, stream>>>(W, WT);
  k12_gemm_softmax<<<512, 256, 0, stream>>>(x, WT, rw_out, top12, wts, histR,
                                            zR);
  k3_dispatch<<<N_TOK / 4, 256, 0, stream>>>(top12, wts, histR, mask_out,
                                             cntR);
  k4_loss<<<1, 64, 0, stream>>>(cntR, zR, loss_out);
}